// Round 13
// baseline (169.722 us; speedup 1.0000x reference)
//
#include <hip/hip_runtime.h>

// ---------------------------------------------------------------------------
// HVIN: maxpool -> composite5x5 conv -> VI scan (32^2, bf16 MFMA, redundant
//       per pair, wave-pipelined) -> upsample -> composite5x5 conv ->
//       VI scan (64^2, bf16 MFMA, split across block pair, boundary-first
//       halo exchange) -> final conv + BN + dueling head
//
// R8:  no per-step __syncthreads in VI loops (neighbor-wave LDS counters).
// R10: both VI loops on MFMA with prebuilt A-fragments.
// R12: s_setprio around compute; s_sleep spins; ds_read_b64 mailboxes.
// R13: COMPILE-TIME boundary-first tile order. R10's OTILE(q8 ^ swap) used a
//      runtime swap -> every Bs*/vsum access was a runtime-indexed register
//      array -> compiler emitted 8-way cndmask select networks per access
//      (VALUBusy rose 36->50% in R10 despite removing the inner weight
//      stream). Branch on block-uniform `half`, literal OTILE args.
//
// ws float layout:
//   [0..49] WeffO  [64..225] GO  [256..305] WeffI  [320..481] GI
//   [512..521] bn_sum  [528..537] bn_sumsq  [544..1823] q_pix[128][10]
//   ints [4096 + bid*32] flags (128 B apart)
//   [16384 + bid*256] halo (1 KB apart)        (ends at 81920)
//   [81920..86016) outer A-fragments (16 KB)
//   [86016..90112) inner A-fragments (16 KB)
// ---------------------------------------------------------------------------

#define NEG_BIG (-3.402823466e38f)
#define SCOPE_AGENT __HIP_MEMORY_SCOPE_AGENT
#define WG_SCOPE    __HIP_MEMORY_SCOPE_WORKGROUP
#define CNT_BIG     0x3FFFFFFF

typedef __attribute__((ext_vector_type(8))) short bf16x8;
typedef __attribute__((ext_vector_type(4))) float f32x4;
typedef __attribute__((ext_vector_type(4))) unsigned int u32x4;

__device__ __forceinline__ unsigned f2bf(float f) {
    unsigned u = __builtin_bit_cast(unsigned, f);
    return (u + 0x7FFFu + ((u >> 16) & 1u)) >> 16;   // RNE f32 -> bf16 bits
}
__device__ __forceinline__ unsigned pk(float a, float b) {
    return f2bf(a) | (f2bf(b) << 16);
}

__global__ void k_precomp(const float* __restrict__ conv_h_w,
                          const float* __restrict__ conv_r_w,
                          const float* __restrict__ vi_h_w,
                          const float* __restrict__ vi_r_w,
                          const float* __restrict__ conv_q_ws,
                          const float* __restrict__ vi_q_ws,
                          float* __restrict__ ws) {
    __shared__ float sG[2][162];
    int t = threadIdx.x; // 1024 threads
    if (t < 324) {
        int set = t / 162;      // 0 = outer, 1 = inner
        int e   = t % 162;
        int ax = e % 3;  int e1 = e / 3;
        int ay = e1 % 3; int e2 = e1 / 3;
        int i  = e2 % 2; int e3 = e2 / 2;
        int bx = e3 % 3; int by = e3 / 3;
        const float* Wh = set ? vi_h_w : conv_h_w;
        const float* Wr = set ? vi_r_w : conv_r_w;
        float acc = 0.f;
        for (int c = 0; c < 150; ++c)
            acc += Wr[(c*3+by)*3+bx] * Wh[((c*2+i)*3+ay)*3+ax];
        sG[set][e] = acc;
        ws[(set ? 320 : 64) + e] = acc;
    }
    if (t >= 480 && t < 512) ws[512 + (t - 480)] = 0.f;   // zero BN accumulators
    for (int i = t; i < 8192; i += 1024) ((int*)ws)[4096 + i] = 0;  // flags
    // ---- outer A-fragments: ws[81920 + t*4 ..] ----
    {
        int s = t >> 6, lane = t & 63;
        int ch = lane & 15, kb = (lane >> 4) * 8;
        unsigned* dst = (unsigned*)(ws + 81920) + t * 4;
        for (int j = 0; j < 4; ++j) {
            int k0 = kb + 2*j, k1 = k0 + 1;
            float w0 = 0.f, w1 = 0.f;
            if (ch < 10) {
                if (k0 < 27) w0 = conv_q_ws[s*270 + ch*27 + k0];
                if (k1 < 27) w1 = conv_q_ws[s*270 + ch*27 + k1];
            }
            dst[j] = f2bf(w0) | (f2bf(w1) << 16);
        }
    }
    // ---- inner A-fragments: ws[86016 + t*4 ..] (K taps: k0-8=r, k9-17=v) ----
    {
        int s = t >> 6, lane = t & 63;
        int ch = lane & 15, kb = (lane >> 4) * 8;
        unsigned* dst = (unsigned*)(ws + 86016) + t * 4;
        for (int j = 0; j < 4; ++j) {
            int k0 = kb + 2*j, k1 = k0 + 1;
            float w0 = 0.f, w1 = 0.f;
            if (ch < 10) {
                if (k0 < 18) w0 = vi_q_ws[s*180 + ch*18 + k0];
                if (k1 < 18) w1 = vi_q_ws[s*180 + ch*18 + k1];
            }
            dst[j] = f2bf(w0) | (f2bf(w1) << 16);
        }
    }
    __syncthreads();
    if (t < 100) {
        int set = t / 50;
        int e   = t % 50;
        int i  = e / 25;
        int oy = (e % 25) / 5;
        int ox = e % 5;
        float acc = 0.f;
        for (int by = 0; by < 3; ++by) {
            int ay = oy - by; if (ay < 0 || ay > 2) continue;
            for (int bx = 0; bx < 3; ++bx) {
                int ax = ox - bx; if (ax < 0 || ax > 2) continue;
                acc += sG[set][(((by*3+bx)*2+i)*3+ay)*3+ax];
            }
        }
        ws[(set ? 256 : 0) + e] = acc;
    }
}

// Mailbox sync: sM[w+1][0] = progress of wave w-1, sM[w+1][1] = progress of
// wave w+1 (sentinels at sM[1][0] and sM[16][1]). One ds_read_b64 per spin
// iteration; s_sleep while waiting (no issue pressure on the SIMD).
#define SPIN_NB2(M, W, K)                                                     \
  { int sp_ = 0;                                                              \
    for (;;) {                                                                \
      long long both_ = __hip_atomic_load(                                    \
          (const long long*)&M[(W)+1][0], __ATOMIC_ACQUIRE, WG_SCOPE);        \
      if ((int)(both_ & 0xFFFFFFFFll) >= (K) &&                               \
          (int)(both_ >> 32) >= (K)) break;                                   \
      __builtin_amdgcn_s_sleep(1);                                            \
      if (++sp_ > (1 << 20)) break;                                           \
    } }
#define REL_NB2(M, W, K)                                                      \
  if ((t & 63) == 0) {                                                        \
    __hip_atomic_store(&M[(W)+2][0], (K), __ATOMIC_RELEASE, WG_SCOPE);        \
    __hip_atomic_store(&M[(W)][1],   (K), __ATOMIC_RELEASE, WG_SCOPE);        \
  }

// ---- one outer 16-px tile (TT must be a LITERAL 0..7) --------------------
#define OTILE(TT)                                                             \
  {                                                                           \
    const int tt_ = (TT);                                                     \
    const int lr  = 2*pp + (tt_ >> 2);                                        \
    const int px  = (tt_ & 3) * 16 + col;                                     \
    unsigned t01 = 0, t23 = 0, t45 = 0, v2 = 0;                               \
    if (g >= 2) {                                                             \
        const unsigned short* vp = &vL[cur][(g == 3) ? (lr + 2) : lr][px];    \
        unsigned v0 = vp[0], v1 = vp[1]; v2 = vp[2];                          \
        unsigned v3 = vp[68], v4 = vp[69], v5 = vp[70];                       \
        t01 = v0 | (v1 << 16);                                                \
        t23 = v2 | (v3 << 16);                                                \
        t45 = v4 | (v5 << 16);                                                \
    }                                                                         \
    union { u32x4 u; bf16x8 b; } bv;                                          \
    bv.u = (u32x4){                                                           \
        (g == 3) ? t01 : Bs0[tt_],                                            \
        (g == 2) ? t01 : ((g == 3) ? v2 : Bs1[tt_]),                          \
        (g == 2) ? t23 : Bs2[tt_],                                            \
        (g == 2) ? t45 : Bs3[tt_]};                                           \
    f32x4 d = __builtin_amdgcn_mfma_f32_16x16x32_bf16(                        \
        av.b, bv.b, (f32x4){0.f, 0.f, 0.f, 0.f}, 0, 0, 0);                    \
    float pm01 = fmaxf(d[0], d[1]);                                           \
    float pm4  = fmaxf(pm01, fmaxf(d[2], d[3]));                              \
    float val  = (g < 2) ? pm4 : ((g == 2) ? pm01 : NEG_BIG);                 \
    val = fmaxf(val, __shfl_xor(val, 16));                                    \
    val = fmaxf(val, __shfl_xor(val, 32));                                    \
    vsum[tt_] += val;                                                         \
    unsigned short vb = (unsigned short)f2bf(val);                            \
    if (lane < 16) vL[nxt][lr + 1][px + 1] = vb;                              \
    const bool btile = half ? (tt_ < 4) : (tt_ >= 4);                         \
    if (K < 15 && rp == 0 && btile && lane < 16)                              \
        ghU[cur * 64 + px] = vb;          /* boundary row -> partner */       \
  }

__global__
__attribute__((amdgpu_flat_work_group_size(1024, 1024)))
void k_main(
    const float* __restrict__ Xg,        // [128][2][64][64]
    const int*   __restrict__ S1,
    const int*   __restrict__ S2,
    const float* __restrict__ conv_q_ws, // [16][10][3][3][3]
    const float* __restrict__ vi_q_ws,   // [16][10][2][3][3]
    const float* __restrict__ ws,        // composites (read-only)
    float*       __restrict__ wsm)       // BN accum + qpix + flags + halo + A
{
    __shared__ float sX[2][64][64];
    __shared__ float sX1[2][32][32];
    __shared__ float sr1[34][34];            // ring-padded r1, later v1 (f32)
    __shared__ float sm[34][66];             // m rows gr0-1..gr0+32 (f32)
    __shared__ float sr[34][66];             // r rows gr0-1..gr0+32 (f32)
    __shared__ float sVb[34][66];            // outer v-SUM (f32)
    __shared__ unsigned short vL[2][35][68]; // outer v ping-pong (bf16)
    __shared__ unsigned short vI[2][34][36]; // inner v ping-pong (bf16)
    __shared__ unsigned int sA [16][64][4];  // outer A-fragments
    __shared__ unsigned int sAI[16][64][4];  // inner A-fragments
    __shared__ float sRed[10][2];
    __shared__ alignas(8) int sMI[18][2];    // inner mailboxes (+sentinels)
    __shared__ alignas(8) int sMO[18][2];    // outer mailboxes (+sentinels)
    // LDS ~120 KB: >80 KB -> exactly 1 block/CU (pair co-residency)

    const int bid  = blockIdx.x;
    const int half = (bid >> 3) & 1;
    const int n    = (bid & 7) | ((bid >> 4) << 3);  // pair (b, b^8) same XCD
    const int gr0  = half << 5;          // first own outer row
    const int t    = threadIdx.x;
    const int rpw  = t >> 6;             // wave id 0..15
    const int lane = t & 63;
    const int g    = lane >> 4;          // B-fragment k-group
    const int col  = lane & 15;

    int*   flagMine = (int*)wsm + 4096 + bid * 32;        // 128 B apart
    int*   flagPart = (int*)wsm + 4096 + (bid ^ 8) * 32;
    float* ghMine   = wsm + 16384 + bid * 256;            // 1 KB apart
    float* ghPart   = wsm + 16384 + (bid ^ 8) * 256;

    // ---- zero-init ring/pad arrays; stage A-fragments; init mailboxes ----
    {
        float* z;
        z = &sr1[0][0]; for (int i = t; i < 1156; i += 1024) z[i] = 0.f;
        z = &sm[0][0];  for (int i = t; i < 2244; i += 1024) z[i] = 0.f;
        z = &sr[0][0];  for (int i = t; i < 2244; i += 1024) z[i] = 0.f;
        z = &sVb[0][0]; for (int i = t; i < 2244; i += 1024) z[i] = 0.f;
        unsigned int* zv = (unsigned int*)&vL[0][0][0];
        for (int i = t; i < 2380; i += 1024) zv[i] = 0u;
        unsigned int* zi = (unsigned int*)&vI[0][0][0];
        for (int i = t; i < 1224; i += 1024) zi[i] = 0u;
        if (t < 20) ((float*)sRed)[t] = 0.f;
        if (t < 36) {
            // sentinels: sMI[1][0] (elem 2) and sMI[16][1] (elem 33)
            int v = (t == 2 || t == 33) ? CNT_BIG : 0;
            ((int*)sMI)[t] = v;
            ((int*)sMO)[t] = v;
        }
        ((u32x4*)&sA [0][0][0])[t] = ((const u32x4*)(wsm + 81920))[t];
        ((u32x4*)&sAI[0][0][0])[t] = ((const u32x4*)(wsm + 86016))[t];
    }
    // ---- P0: load full X (coalesced float4) ----
    {
        const float4* src = (const float4*)(Xg + (size_t)n * 8192);
        float4* dst = (float4*)&sX[0][0][0];
        dst[t] = src[t];
        dst[t + 1024] = src[t + 1024];
    }
    __syncthreads();

    // ---- P1: maxpool 2x2 -> sX1 ----
    for (int idx = t; idx < 2048; idx += 1024) {
        int c = idx >> 10;
        int y = (idx >> 5) & 31;
        int x = idx & 31;
        float a0 = sX[c][2*y][2*x],   a1 = sX[c][2*y][2*x+1];
        float a2 = sX[c][2*y+1][2*x], a3 = sX[c][2*y+1][2*x+1];
        sX1[c][y][x] = fmaxf(fmaxf(a0, a1), fmaxf(a2, a3));
    }
    __syncthreads();

    // ---- P2: r1 = composite 5x5 conv(X1) + border correction (redundant) ----
    const int iy = t >> 5, ix = t & 31;   // 1 px/thread on the 32x32 grid
    {
        const float* WeffI = ws + 256;
        const float* GI    = ws + 320;
        float acc = 0.f;
        for (int i = 0; i < 2; ++i)
            for (int oy = 0; oy < 5; ++oy) {
                int yy = iy + oy - 2; if (yy < 0 || yy >= 32) continue;
                for (int ox = 0; ox < 5; ++ox) {
                    int xx = ix + ox - 2; if (xx < 0 || xx >= 32) continue;
                    acc += WeffI[i*25 + oy*5 + ox] * sX1[i][yy][xx];
                }
            }
        if (iy == 0 || iy == 31 || ix == 0 || ix == 31) {
            float corr = 0.f;
            for (int by = 0; by < 3; ++by)
                for (int bx = 0; bx < 3; ++bx) {
                    int qy = iy + by - 1, qx = ix + bx - 1;
                    if (qy >= 0 && qy < 32 && qx >= 0 && qx < 32) continue;
                    const float* Gb = GI + (by*3+bx)*18;
                    for (int i = 0; i < 2; ++i)
                        for (int ay = 0; ay < 3; ++ay) {
                            int yy2 = qy + ay - 1; if (yy2 < 0 || yy2 >= 32) continue;
                            for (int ax = 0; ax < 3; ++ax) {
                                int xx2 = qx + ax - 1; if (xx2 < 0 || xx2 >= 32) continue;
                                corr += Gb[i*9 + ay*3 + ax] * sX1[i][yy2][xx2];
                            }
                        }
                }
            acc -= corr;
        }
        sr1[1+iy][1+ix] = acc;
    }
    __syncthreads();

    // ---- P3: inner VI via MFMA (16 steps, mailbox sync + setprio) ----
    {
        unsigned BsI0[4], BsI1[4], BsI2[4], BsI3[4];
        #pragma unroll
        for (int tt = 0; tt < 4; ++tt) {
            const int lr = 2*rpw + (tt >> 1);
            const int px = (tt & 1) * 16 + col;
            unsigned a0 = 0, a1 = 0, a2 = 0, a3 = 0;
            if (g == 0) {            // k0-7 = r taps 0-7
                a0 = pk(sr1[lr][px],     sr1[lr][px+1]);
                a1 = pk(sr1[lr][px+2],   sr1[lr+1][px]);
                a2 = pk(sr1[lr+1][px+1], sr1[lr+1][px+2]);
                a3 = pk(sr1[lr+2][px],   sr1[lr+2][px+1]);
            } else if (g == 1) {     // k8 = r tap 8 (low half of dword0)
                a0 = f2bf(sr1[lr+2][px+2]);
            }
            BsI0[tt] = a0; BsI1[tt] = a1; BsI2[tt] = a2; BsI3[tt] = a3;
            asm volatile("" : "+v"(BsI0[tt]), "+v"(BsI1[tt]),
                              "+v"(BsI2[tt]), "+v"(BsI3[tt]));
        }
        float vsumI[4] = {0.f, 0.f, 0.f, 0.f};
        for (int K = 0; K < 16; ++K) {
            const int cur = K & 1, nxt = cur ^ 1;
            union { u32x4 u; bf16x8 b; } av;
            av.u = *(const u32x4*)&sAI[K][lane][0];
            SPIN_NB2(sMI, rpw, K);
            __builtin_amdgcn_s_setprio(1);
            #pragma unroll
            for (int tt = 0; tt < 4; ++tt) {
                const int lr = 2*rpw + (tt >> 1);
                const int px = (tt & 1) * 16 + col;
                unsigned d0, d1, d2, d3;
                if (g == 1) {        // k9-15 = v taps 0-6
                    const unsigned short* vp = &vI[cur][lr][px];
                    unsigned w0 = vp[0], w1 = vp[1], w2v = vp[2];
                    unsigned w3 = vp[36], w4 = vp[37], w5 = vp[38];
                    unsigned w6 = vp[72];
                    d0 = BsI0[tt] | (w0 << 16);
                    d1 = w1 | (w2v << 16);
                    d2 = w3 | (w4 << 16);
                    d3 = w5 | (w6 << 16);
                } else if (g == 2) { // k16,17 = v taps 7,8
                    const unsigned short* vp = &vI[cur][lr+2][px+1];
                    d0 = (unsigned)vp[0] | (((unsigned)vp[1]) << 16);
                    d1 = 0; d2 = 0; d3 = 0;
                } else if (g == 0) {
                    d0 = BsI0[tt]; d1 = BsI1[tt]; d2 = BsI2[tt]; d3 = BsI3[tt];
                } else {
                    d0 = 0; d1 = 0; d2 = 0; d3 = 0;
                }
                union { u32x4 u; bf16x8 b; } bv;
                bv.u = (u32x4){d0, d1, d2, d3};
                f32x4 d = __builtin_amdgcn_mfma_f32_16x16x32_bf16(
                    av.b, bv.b, (f32x4){0.f, 0.f, 0.f, 0.f}, 0, 0, 0);
                float pm01 = fmaxf(d[0], d[1]);
                float pm4  = fmaxf(pm01, fmaxf(d[2], d[3]));
                float val  = (g < 2) ? pm4 : ((g == 2) ? pm01 : NEG_BIG);
                val = fmaxf(val, __shfl_xor(val, 16));
                val = fmaxf(val, __shfl_xor(val, 32));
                vsumI[tt] += val;
                if (lane < 16) vI[nxt][lr + 1][px + 1] = (unsigned short)f2bf(val);
            }
            __builtin_amdgcn_s_setprio(0);
            REL_NB2(sMI, rpw, K + 1);
        }
        // v1 = sum/4 -> sr1
        #pragma unroll
        for (int tt = 0; tt < 4; ++tt) {
            const int lr = 2*rpw + (tt >> 1);
            const int px = (tt & 1) * 16 + col;
            if (lane < 16) sr1[lr + 1][px + 1] = vsumI[tt] * 0.25f;
        }
    }
    __syncthreads();

    // ---- P4+P5: m = upsample(v1), r = composite conv(X); rows gr0-1..gr0+32
    {
        const float* WeffO = ws;
        const float* GO    = ws + 64;
        int c = t & 63;
        for (int ar = t >> 6; ar < 34; ar += 16) {
            int gg = gr0 + ar - 1;
            if ((unsigned)gg < 64u) {
                int y0, y1; float wy0, wy1;
                if ((gg & 1) == 0) { y1 = gg >> 1; y0 = (y1 > 0) ? y1 - 1 : 0; wy1 = 0.75f; wy0 = 0.25f; }
                else               { y0 = gg >> 1; y1 = (y0 < 31) ? y0 + 1 : 31; wy0 = 0.75f; wy1 = 0.25f; }
                int xa, xb; float wx0, wx1;
                if ((c & 1) == 0) { xb = c >> 1; xa = (xb > 0) ? xb - 1 : 0; wx1 = 0.75f; wx0 = 0.25f; }
                else              { xa = c >> 1; xb = (xa < 31) ? xa + 1 : 31; wx0 = 0.75f; wx1 = 0.25f; }
                sm[ar][1+c] = wy0 * (wx0 * sr1[1+y0][1+xa] + wx1 * sr1[1+y0][1+xb])
                            + wy1 * (wx0 * sr1[1+y1][1+xa] + wx1 * sr1[1+y1][1+xb]);
                float acc = 0.f;
                for (int i = 0; i < 2; ++i)
                    for (int oy = 0; oy < 5; ++oy) {
                        int yy = gg + oy - 2; if (yy < 0 || yy >= 64) continue;
                        for (int ox = 0; ox < 5; ++ox) {
                            int xx = c + ox - 2; if (xx < 0 || xx >= 64) continue;
                            acc += WeffO[i*25 + oy*5 + ox] * sX[i][yy][xx];
                        }
                    }
                if (gg == 0 || gg == 63 || c == 0 || c == 63) {
                    float corr = 0.f;
                    for (int by = 0; by < 3; ++by)
                        for (int bx = 0; bx < 3; ++bx) {
                            int qy = gg + by - 1, qx = c + bx - 1;
                            if (qy >= 0 && qy < 64 && qx >= 0 && qx < 64) continue;
                            const float* Gb = GO + (by*3+bx)*18;
                            for (int i = 0; i < 2; ++i)
                                for (int ay = 0; ay < 3; ++ay) {
                                    int yy2 = qy + ay - 1; if (yy2 < 0 || yy2 >= 64) continue;
                                    for (int ax = 0; ax < 3; ++ax) {
                                        int xx2 = qx + ax - 1; if (xx2 < 0 || xx2 >= 64) continue;
                                        corr += Gb[i*9 + ay*3 + ax] * sX[i][yy2][xx2];
                                    }
                                }
                        }
                    acc -= corr;
                }
                sr[ar][1+c] = acc;
            }
        }
    }
    __syncthreads();

    // ---- P6: outer VI via MFMA, boundary-first (compile-time order) ----
    const int rp   = rpw;                     // wave id
    const int pp   = half ? rp : (15 - rp);   // local row-pair index
    const int gRowV = half ? 0 : 33;          // bf16 ghost row

    // static B fragments (m,r slices), 4 regs x 8 tiles -- pinned
    unsigned Bs0[8], Bs1[8], Bs2[8], Bs3[8];
    #pragma unroll
    for (int tt = 0; tt < 8; ++tt) {
        const int lr = 2*pp + (tt >> 2);
        const int px = (tt & 3) * 16 + col;
        unsigned a0 = 0, a1 = 0, a2 = 0, a3 = 0;
        if (g == 0) {            // k0-7 = m taps 0-7
            a0 = pk(sm[lr][px],     sm[lr][px+1]);
            a1 = pk(sm[lr][px+2],   sm[lr+1][px]);
            a2 = pk(sm[lr+1][px+1], sm[lr+1][px+2]);
            a3 = pk(sm[lr+2][px],   sm[lr+2][px+1]);
        } else if (g == 1) {     // k8-15 = m tap 8, r taps 0-6
            a0 = pk(sm[lr+2][px+2], sr[lr][px]);
            a1 = pk(sr[lr][px+1],   sr[lr][px+2]);
            a2 = pk(sr[lr+1][px],   sr[lr+1][px+1]);
            a3 = pk(sr[lr+1][px+2], sr[lr+2][px]);
        } else if (g == 2) {     // k16-17 = r taps 7,8 (k18-23 = v, dynamic)
            a0 = pk(sr[lr+2][px+1], sr[lr+2][px+2]);
        }                        // g3: k24-26 = v (dynamic), k27-31 = 0
        Bs0[tt] = a0; Bs1[tt] = a1; Bs2[tt] = a2; Bs3[tt] = a3;
        asm volatile("" : "+v"(Bs0[tt]), "+v"(Bs1[tt]),
                          "+v"(Bs2[tt]), "+v"(Bs3[tt]));
    }

    float vsum[8];
    #pragma unroll
    for (int j = 0; j < 8; ++j) vsum[j] = 0.f;

    unsigned short*       ghU = (unsigned short*)ghMine;
    const unsigned short* gpU = (const unsigned short*)ghPart;

    for (int K = 0; K < 16; ++K) {
        const int cur = K & 1, nxt = cur ^ 1;
        union { u32x4 u; bf16x8 b; } av;
        av.u = *(const u32x4*)&sA[K][lane][0];   // static; overlaps spin
        SPIN_NB2(sMO, rp, K);                    // neighbors' v_K rows ready
        __builtin_amdgcn_s_setprio(1);
        // Boundary tiles first, with LITERAL tile indices (block-uniform
        // branch on `half`); flag posted mid-step between the halves.
        if (!half) {   // boundary = tt 4-7 (local row 2pp+1)
            OTILE(4); OTILE(5); OTILE(6); OTILE(7);
            if (K < 15 && t == 0)
                __hip_atomic_store(flagMine, K + 1, __ATOMIC_RELEASE, SCOPE_AGENT);
            OTILE(0); OTILE(1); OTILE(2); OTILE(3);
        } else {       // boundary = tt 0-3 (local row 2pp)
            OTILE(0); OTILE(1); OTILE(2); OTILE(3);
            if (K < 15 && t == 0)
                __hip_atomic_store(flagMine, K + 1, __ATOMIC_RELEASE, SCOPE_AGENT);
            OTILE(4); OTILE(5); OTILE(6); OTILE(7);
        }
        __builtin_amdgcn_s_setprio(0);
        // early neighbor release (ghost row consumed only by wave 0 itself)
        REL_NB2(sMO, rp, K + 1);
        // deferred poll: partner posted its flag mid-step -> usually no wait
        if (K < 15 && rp == 0) {
            if (t == 0) {
                int spins = 0;
                while (__hip_atomic_load(flagPart, __ATOMIC_ACQUIRE, SCOPE_AGENT) < K + 1) {
                    __builtin_amdgcn_s_sleep(1);
                    if (++spins > (1 << 23)) break;   // safety valve
                }
            }
            vL[nxt][gRowV][lane + 1] = gpU[cur * 64 + lane];
        }
    }
    __syncthreads();

    // ---- v-sum -> sVb; exchange boundary sums (f32, flag 16) ----
    #pragma unroll
    for (int tt = 0; tt < 8; ++tt) {
        const int lr = 2*pp + (tt >> 2);
        const int px = (tt & 3) * 16 + col;
        if (lane < 16) sVb[lr + 1][px + 1] = vsum[tt];
    }
    if (rp == 0) {
        const int bAr = half ? 1 : 32;   // own boundary row (written above)
        const int gAr = half ? 0 : 33;   // ghost row
        float sv = sVb[bAr][1 + lane];
        __hip_atomic_store(ghMine + 128 + lane, sv, __ATOMIC_RELAXED, SCOPE_AGENT);
        if (t == 0) {
            __hip_atomic_store(flagMine, 16, __ATOMIC_RELEASE, SCOPE_AGENT);
            int spins = 0;
            while (__hip_atomic_load(flagPart, __ATOMIC_ACQUIRE, SCOPE_AGENT) < 16) {
                __builtin_amdgcn_s_sleep(1);
                if (++spins > (1 << 23)) break;
            }
        }
        sVb[gAr][1 + lane] =
            __hip_atomic_load(ghPart + 128 + lane, __ATOMIC_RELAXED, SCOPE_AGENT);
    }
    __syncthreads();

    // ---- P7: final conv (w15) on {m, r, vbar=sum/16} + BN + (S1,S2) pick ----
    {
        const float* wk = conv_q_ws + 15 * 270;
        const int oc = lane;
        float pm[4][3], pq[4][3], pv[4][3];
        #pragma unroll
        for (int dy = 0; dy < 4; ++dy)
            #pragma unroll
            for (int dx = 0; dx < 3; ++dx) {
                pm[dy][dx] = sm[2*pp+dy][oc+dx];
                pq[dy][dx] = sr[2*pp+dy][oc+dx];
                pv[dy][dx] = sVb[2*pp+dy][oc+dx] * 0.0625f;
            }
        int sy = S1[n], sx = S2[n];
        int ry0 = gr0 + 2*pp, ry1 = ry0 + 1;
        float* qpix = wsm + 544 + n * 10;
        #pragma unroll
        for (int ch = 0; ch < 10; ++ch) {
            const float* wc = wk + ch * 27;
            float q0 = 0.f, q1 = 0.f;
            #pragma unroll
            for (int ky = 0; ky < 3; ++ky)
                #pragma unroll
                for (int kx = 0; kx < 3; ++kx) {
                    float wm = wc[ky*3+kx];
                    float wr = wc[9  + ky*3+kx];
                    float wv = wc[18 + ky*3+kx];
                    q0 += wm * pm[ky][kx]   + wr * pq[ky][kx]   + wv * pv[ky][kx];
                    q1 += wm * pm[ky+1][kx] + wr * pq[ky+1][kx] + wv * pv[ky+1][kx];
                }
            if (oc == sx) {
                if (ry0 == sy) qpix[ch] = q0;
                if (ry1 == sy) qpix[ch] = q1;
            }
            float ls = q0 + q1, lq = q0*q0 + q1*q1;
            #pragma unroll
            for (int off = 32; off > 0; off >>= 1) {
                ls += __shfl_down(ls, off);
                lq += __shfl_down(lq, off);
            }
            if ((t & 63) == 0) {
                atomicAdd(&sRed[ch][0], ls);
                atomicAdd(&sRed[ch][1], lq);
            }
        }
        __syncthreads();
        if (t < 10) {
            atomicAdd(wsm + 512 + t, sRed[t][0]);
            atomicAdd(wsm + 528 + t, sRed[t][1]);
        }
    }
}

__global__ void k_final(const float* __restrict__ ws,
                        const float* __restrict__ gamma,
                        const float* __restrict__ beta,
                        const float* __restrict__ w1,
                        const float* __restrict__ w2,
                        float* __restrict__ out) {
    int n = threadIdx.x;
    if (n >= 128) return;
    const float inv = 1.f / 524288.f;
    float qn[10];
    for (int c = 0; c < 10; ++c) {
        float mean = ws[512 + c] * inv;
        float var  = ws[528 + c] * inv - mean * mean;
        float q    = ws[544 + n * 10 + c];
        qn[c] = (q - mean) * rsqrtf(var + 1e-5f) * gamma[c] + beta[c];
    }
    float a = 0.f;
    for (int c = 0; c < 10; ++c) a += qn[c] * w1[c];
    a = fmaxf(a, 0.f);
    float b[8], mb = 0.f;
    for (int j = 0; j < 8; ++j) {
        float bj = 0.f;
        for (int c = 0; c < 10; ++c) bj += qn[c] * w2[j * 10 + c];
        bj = fmaxf(bj, 0.f);
        b[j] = bj;
        mb += bj;
    }
    mb *= 0.125f;
    for (int j = 0; j < 8; ++j) out[n * 8 + j] = a + b[j] - mb;
}

extern "C" void kernel_launch(void* const* d_in, const int* in_sizes, int n_in,
                              void* d_out, int out_size, void* d_ws, size_t ws_size,
                              hipStream_t stream) {
    const float* X         = (const float*)d_in[0];
    const int*   S1        = (const int*)  d_in[1];
    const int*   S2        = (const int*)  d_in[2];
    const float* conv_h_w  = (const float*)d_in[3];
    const float* conv_r_w  = (const float*)d_in[4];
    const float* conv_q_ws = (const float*)d_in[5];
    const float* bn_gamma  = (const float*)d_in[6];
    const float* bn_beta   = (const float*)d_in[7];
    const float* duel_w1   = (const float*)d_in[8];
    const float* duel_w2   = (const float*)d_in[9];
    const float* vi_h_w    = (const float*)d_in[10];
    const float* vi_r_w    = (const float*)d_in[11];
    const float* vi_q_ws   = (const float*)d_in[12];
    float* ws = (float*)d_ws;

    k_precomp<<<1, 1024, 0, stream>>>(conv_h_w, conv_r_w, vi_h_w, vi_r_w,
                                      conv_q_ws, vi_q_ws, ws);
    k_main<<<256, 1024, 0, stream>>>(X, S1, S2, conv_q_ws, vi_q_ws, ws, ws);
    k_final<<<1, 128, 0, stream>>>(ws, bn_gamma, bn_beta, duel_w1, duel_w2,
                                   (float*)d_out);
}

// Round 14
// 168.304 us; speedup vs baseline: 1.0084x; 1.0084x over previous
//
#include <hip/hip_runtime.h>

// ---------------------------------------------------------------------------
// HVIN: maxpool -> composite5x5 conv -> VI scan (32^2, bf16 MFMA, 8 waves,
//       overlapped with the outer conv on waves 8-15) -> upsample ->
//       VI scan (64^2, bf16 MFMA, 16 waves, split across block pair) ->
//       final conv + BN + dueling head
//
// R8/R10/R12/R13 machinery kept (mailbox wave sync, prebuilt A-fragments,
// setprio, compile-time tile order, padded cross-pair flags).
// R14: WAVE SPECIALIZATION. After P0/P1 (all waves + barrier):
//        waves 0-7 : P2 (r1 conv, own 4-row band) -> mailbox sync ->
//                    inner VI (4 rows/wave, 8 tiles/step, 8-deep chain)
//        waves 8-15: P5 (outer composite conv r -> sr) concurrently
//      join barrier -> P4 (m upsample) -> outer VI (16 waves) -> P7.
//      Removes P2+P5 from the serial timeline and halves the inner
//      sync-chain depth. Inner mailbox counters: P2 done = 1, step K
//      releases K+2.
//
// ws float layout:
//   [0..49] WeffO  [64..225] GO  [256..305] WeffI  [320..481] GI
//   [512..521] bn_sum  [528..537] bn_sumsq  [544..1823] q_pix[128][10]
//   ints [4096 + bid*32] flags (128 B apart)
//   [16384 + bid*256] halo (1 KB apart)        (ends at 81920)
//   [81920..86016) outer A-fragments (16 KB)
//   [86016..90112) inner A-fragments (16 KB)
// ---------------------------------------------------------------------------

#define NEG_BIG (-3.402823466e38f)
#define SCOPE_AGENT __HIP_MEMORY_SCOPE_AGENT
#define WG_SCOPE    __HIP_MEMORY_SCOPE_WORKGROUP
#define CNT_BIG     0x3FFFFFFF

typedef __attribute__((ext_vector_type(8))) short bf16x8;
typedef __attribute__((ext_vector_type(4))) float f32x4;
typedef __attribute__((ext_vector_type(4))) unsigned int u32x4;

__device__ __forceinline__ unsigned f2bf(float f) {
    unsigned u = __builtin_bit_cast(unsigned, f);
    return (u + 0x7FFFu + ((u >> 16) & 1u)) >> 16;   // RNE f32 -> bf16 bits
}
__device__ __forceinline__ unsigned pk(float a, float b) {
    return f2bf(a) | (f2bf(b) << 16);
}

__global__ void k_precomp(const float* __restrict__ conv_h_w,
                          const float* __restrict__ conv_r_w,
                          const float* __restrict__ vi_h_w,
                          const float* __restrict__ vi_r_w,
                          const float* __restrict__ conv_q_ws,
                          const float* __restrict__ vi_q_ws,
                          float* __restrict__ ws) {
    __shared__ float sG[2][162];
    int t = threadIdx.x; // 1024 threads
    if (t < 324) {
        int set = t / 162;      // 0 = outer, 1 = inner
        int e   = t % 162;
        int ax = e % 3;  int e1 = e / 3;
        int ay = e1 % 3; int e2 = e1 / 3;
        int i  = e2 % 2; int e3 = e2 / 2;
        int bx = e3 % 3; int by = e3 / 3;
        const float* Wh = set ? vi_h_w : conv_h_w;
        const float* Wr = set ? vi_r_w : conv_r_w;
        float acc = 0.f;
        for (int c = 0; c < 150; ++c)
            acc += Wr[(c*3+by)*3+bx] * Wh[((c*2+i)*3+ay)*3+ax];
        sG[set][e] = acc;
        ws[(set ? 320 : 64) + e] = acc;
    }
    if (t >= 480 && t < 512) ws[512 + (t - 480)] = 0.f;   // zero BN accumulators
    for (int i = t; i < 8192; i += 1024) ((int*)ws)[4096 + i] = 0;  // flags
    // ---- outer A-fragments: ws[81920 + t*4 ..] ----
    {
        int s = t >> 6, lane = t & 63;
        int ch = lane & 15, kb = (lane >> 4) * 8;
        unsigned* dst = (unsigned*)(ws + 81920) + t * 4;
        for (int j = 0; j < 4; ++j) {
            int k0 = kb + 2*j, k1 = k0 + 1;
            float w0 = 0.f, w1 = 0.f;
            if (ch < 10) {
                if (k0 < 27) w0 = conv_q_ws[s*270 + ch*27 + k0];
                if (k1 < 27) w1 = conv_q_ws[s*270 + ch*27 + k1];
            }
            dst[j] = f2bf(w0) | (f2bf(w1) << 16);
        }
    }
    // ---- inner A-fragments: ws[86016 + t*4 ..] (K taps: k0-8=r, k9-17=v) ----
    {
        int s = t >> 6, lane = t & 63;
        int ch = lane & 15, kb = (lane >> 4) * 8;
        unsigned* dst = (unsigned*)(ws + 86016) + t * 4;
        for (int j = 0; j < 4; ++j) {
            int k0 = kb + 2*j, k1 = k0 + 1;
            float w0 = 0.f, w1 = 0.f;
            if (ch < 10) {
                if (k0 < 18) w0 = vi_q_ws[s*180 + ch*18 + k0];
                if (k1 < 18) w1 = vi_q_ws[s*180 + ch*18 + k1];
            }
            dst[j] = f2bf(w0) | (f2bf(w1) << 16);
        }
    }
    __syncthreads();
    if (t < 100) {
        int set = t / 50;
        int e   = t % 50;
        int i  = e / 25;
        int oy = (e % 25) / 5;
        int ox = e % 5;
        float acc = 0.f;
        for (int by = 0; by < 3; ++by) {
            int ay = oy - by; if (ay < 0 || ay > 2) continue;
            for (int bx = 0; bx < 3; ++bx) {
                int ax = ox - bx; if (ax < 0 || ax > 2) continue;
                acc += sG[set][(((by*3+bx)*2+i)*3+ay)*3+ax];
            }
        }
        ws[(set ? 256 : 0) + e] = acc;
    }
}

// Mailbox sync: sM[w+1][0] = progress of wave w-1, sM[w+1][1] = progress of
// wave w+1 (sentinels padded). One ds_read_b64 per spin iteration; s_sleep
// while waiting (no issue pressure on the SIMD).
#define SPIN_NB2(M, W, K)                                                     \
  { int sp_ = 0;                                                              \
    for (;;) {                                                                \
      long long both_ = __hip_atomic_load(                                    \
          (const long long*)&M[(W)+1][0], __ATOMIC_ACQUIRE, WG_SCOPE);        \
      if ((int)(both_ & 0xFFFFFFFFll) >= (K) &&                               \
          (int)(both_ >> 32) >= (K)) break;                                   \
      __builtin_amdgcn_s_sleep(1);                                            \
      if (++sp_ > (1 << 20)) break;                                           \
    } }
#define REL_NB2(M, W, K)                                                      \
  if ((t & 63) == 0) {                                                        \
    __hip_atomic_store(&M[(W)+2][0], (K), __ATOMIC_RELEASE, WG_SCOPE);        \
    __hip_atomic_store(&M[(W)][1],   (K), __ATOMIC_RELEASE, WG_SCOPE);        \
  }

// ---- one inner 16-px tile (TT literal 0..7); wave owns rows 4w..4w+3 -----
#define ITILE(TT)                                                             \
  {                                                                           \
    const int tt_ = (TT);                                                     \
    const int lr  = 4*rpw + (tt_ >> 1);                                       \
    const int px  = (tt_ & 1) * 16 + col;                                     \
    unsigned d0, d1, d2, d3;                                                  \
    if (g == 1) {        /* k9-15 = v taps 0-6 */                             \
        const unsigned short* vp = &vI[cur][lr][px];                          \
        unsigned w0 = vp[0], w1 = vp[1], w2v = vp[2];                         \
        unsigned w3 = vp[36], w4 = vp[37], w5 = vp[38];                       \
        unsigned w6 = vp[72];                                                 \
        d0 = BsI0[tt_] | (w0 << 16);                                          \
        d1 = w1 | (w2v << 16);                                                \
        d2 = w3 | (w4 << 16);                                                 \
        d3 = w5 | (w6 << 16);                                                 \
    } else if (g == 2) { /* k16,17 = v taps 7,8 */                            \
        const unsigned short* vp = &vI[cur][lr+2][px+1];                      \
        d0 = (unsigned)vp[0] | (((unsigned)vp[1]) << 16);                     \
        d1 = 0; d2 = 0; d3 = 0;                                               \
    } else if (g == 0) {                                                      \
        d0 = BsI0[tt_]; d1 = BsI1[tt_]; d2 = BsI2[tt_]; d3 = BsI3[tt_];       \
    } else {                                                                  \
        d0 = 0; d1 = 0; d2 = 0; d3 = 0;                                       \
    }                                                                         \
    union { u32x4 u; bf16x8 b; } bv;                                          \
    bv.u = (u32x4){d0, d1, d2, d3};                                           \
    f32x4 d = __builtin_amdgcn_mfma_f32_16x16x32_bf16(                        \
        av.b, bv.b, (f32x4){0.f, 0.f, 0.f, 0.f}, 0, 0, 0);                    \
    float pm01 = fmaxf(d[0], d[1]);                                           \
    float pm4  = fmaxf(pm01, fmaxf(d[2], d[3]));                              \
    float val  = (g < 2) ? pm4 : ((g == 2) ? pm01 : NEG_BIG);                 \
    val = fmaxf(val, __shfl_xor(val, 16));                                    \
    val = fmaxf(val, __shfl_xor(val, 32));                                    \
    vsumI[tt_] += val;                                                        \
    if (lane < 16) vI[nxt][lr + 1][px + 1] = (unsigned short)f2bf(val);       \
  }

// ---- one outer 16-px tile (TT must be a LITERAL 0..7) --------------------
#define OTILE(TT)                                                             \
  {                                                                           \
    const int tt_ = (TT);                                                     \
    const int lr  = 2*pp + (tt_ >> 2);                                        \
    const int px  = (tt_ & 3) * 16 + col;                                     \
    unsigned t01 = 0, t23 = 0, t45 = 0, v2 = 0;                               \
    if (g >= 2) {                                                             \
        const unsigned short* vp = &vL[cur][(g == 3) ? (lr + 2) : lr][px];    \
        unsigned v0 = vp[0], v1 = vp[1]; v2 = vp[2];                          \
        unsigned v3 = vp[68], v4 = vp[69], v5 = vp[70];                       \
        t01 = v0 | (v1 << 16);                                                \
        t23 = v2 | (v3 << 16);                                                \
        t45 = v4 | (v5 << 16);                                                \
    }                                                                         \
    union { u32x4 u; bf16x8 b; } bv;                                          \
    bv.u = (u32x4){                                                           \
        (g == 3) ? t01 : Bs0[tt_],                                            \
        (g == 2) ? t01 : ((g == 3) ? v2 : Bs1[tt_]),                          \
        (g == 2) ? t23 : Bs2[tt_],                                            \
        (g == 2) ? t45 : Bs3[tt_]};                                           \
    f32x4 d = __builtin_amdgcn_mfma_f32_16x16x32_bf16(                        \
        av.b, bv.b, (f32x4){0.f, 0.f, 0.f, 0.f}, 0, 0, 0);                    \
    float pm01 = fmaxf(d[0], d[1]);                                           \
    float pm4  = fmaxf(pm01, fmaxf(d[2], d[3]));                              \
    float val  = (g < 2) ? pm4 : ((g == 2) ? pm01 : NEG_BIG);                 \
    val = fmaxf(val, __shfl_xor(val, 16));                                    \
    val = fmaxf(val, __shfl_xor(val, 32));                                    \
    vsum[tt_] += val;                                                         \
    unsigned short vb = (unsigned short)f2bf(val);                            \
    if (lane < 16) vL[nxt][lr + 1][px + 1] = vb;                              \
    const bool btile = half ? (tt_ < 4) : (tt_ >= 4);                         \
    if (K < 15 && rp == 0 && btile && lane < 16)                              \
        ghU[cur * 64 + px] = vb;          /* boundary row -> partner */       \
  }

__global__
__attribute__((amdgpu_flat_work_group_size(1024, 1024)))
void k_main(
    const float* __restrict__ Xg,        // [128][2][64][64]
    const int*   __restrict__ S1,
    const int*   __restrict__ S2,
    const float* __restrict__ conv_q_ws, // [16][10][3][3][3]
    const float* __restrict__ vi_q_ws,   // [16][10][2][3][3]
    const float* __restrict__ ws,        // composites (read-only)
    float*       __restrict__ wsm)       // BN accum + qpix + flags + halo + A
{
    __shared__ float sX[2][64][64];
    __shared__ float sX1[2][32][32];
    __shared__ float sr1[34][34];            // ring-padded r1, later v1 (f32)
    __shared__ float sm[34][66];             // m rows gr0-1..gr0+32 (f32)
    __shared__ float sr[34][66];             // r rows gr0-1..gr0+32 (f32)
    __shared__ float sVb[34][66];            // outer v-SUM (f32)
    __shared__ unsigned short vL[2][35][68]; // outer v ping-pong (bf16)
    __shared__ unsigned short vI[2][34][36]; // inner v ping-pong (bf16)
    __shared__ unsigned int sA [16][64][4];  // outer A-fragments
    __shared__ unsigned int sAI[16][64][4];  // inner A-fragments
    __shared__ float sRed[10][2];
    __shared__ alignas(8) int sMI[10][2];    // inner mailboxes (8 waves)
    __shared__ alignas(8) int sMO[18][2];    // outer mailboxes (16 waves)
    // LDS ~120 KB: >80 KB -> exactly 1 block/CU (pair co-residency)

    const int bid  = blockIdx.x;
    const int half = (bid >> 3) & 1;
    const int n    = (bid & 7) | ((bid >> 4) << 3);  // pair (b, b^8) same XCD
    const int gr0  = half << 5;          // first own outer row
    const int t    = threadIdx.x;
    const int rpw  = t >> 6;             // wave id 0..15
    const int lane = t & 63;
    const int g    = lane >> 4;          // B-fragment k-group
    const int col  = lane & 15;

    int*   flagMine = (int*)wsm + 4096 + bid * 32;        // 128 B apart
    int*   flagPart = (int*)wsm + 4096 + (bid ^ 8) * 32;
    float* ghMine   = wsm + 16384 + bid * 256;            // 1 KB apart
    float* ghPart   = wsm + 16384 + (bid ^ 8) * 256;

    // ---- zero-init ring/pad arrays; stage A-fragments; init mailboxes ----
    {
        float* z;
        z = &sr1[0][0]; for (int i = t; i < 1156; i += 1024) z[i] = 0.f;
        z = &sm[0][0];  for (int i = t; i < 2244; i += 1024) z[i] = 0.f;
        z = &sr[0][0];  for (int i = t; i < 2244; i += 1024) z[i] = 0.f;
        z = &sVb[0][0]; for (int i = t; i < 2244; i += 1024) z[i] = 0.f;
        unsigned int* zv = (unsigned int*)&vL[0][0][0];
        for (int i = t; i < 2380; i += 1024) zv[i] = 0u;
        unsigned int* zi = (unsigned int*)&vI[0][0][0];
        for (int i = t; i < 1224; i += 1024) zi[i] = 0u;
        if (t < 20) ((float*)sRed)[t] = 0.f;
        if (t < 20)   // inner: sentinels at sMI[1][0] (elem 2), sMI[8][1] (17)
            ((int*)sMI)[t] = (t == 2 || t == 17) ? CNT_BIG : 0;
        if (t < 36)   // outer: sentinels at sMO[1][0] (elem 2), sMO[16][1] (33)
            ((int*)sMO)[t] = (t == 2 || t == 33) ? CNT_BIG : 0;
        ((u32x4*)&sA [0][0][0])[t] = ((const u32x4*)(wsm + 81920))[t];
        ((u32x4*)&sAI[0][0][0])[t] = ((const u32x4*)(wsm + 86016))[t];
    }
    // ---- P0: load full X (coalesced float4) ----
    {
        const float4* src = (const float4*)(Xg + (size_t)n * 8192);
        float4* dst = (float4*)&sX[0][0][0];
        dst[t] = src[t];
        dst[t + 1024] = src[t + 1024];
    }
    __syncthreads();

    // ---- P1: maxpool 2x2 -> sX1 (all waves) ----
    for (int idx = t; idx < 2048; idx += 1024) {
        int c = idx >> 10;
        int y = (idx >> 5) & 31;
        int x = idx & 31;
        float a0 = sX[c][2*y][2*x],   a1 = sX[c][2*y][2*x+1];
        float a2 = sX[c][2*y+1][2*x], a3 = sX[c][2*y+1][2*x+1];
        sX1[c][y][x] = fmaxf(fmaxf(a0, a1), fmaxf(a2, a3));
    }
    __syncthreads();

    // ======================= SPECIALIZED SECTION ==========================
    if (t < 512) {
        // ---------------- waves 0-7: P2 (own band) + inner VI -------------
        const float* WeffI = ws + 256;
        const float* GI    = ws + 320;
        // P2: wave w computes r1 rows 4w..4w+3 (2 px per lane)
        #pragma unroll
        for (int rep = 0; rep < 2; ++rep) {
            int q  = rep * 64 + lane;
            int iy2 = 4 * rpw + (q >> 5);
            int ix2 = q & 31;
            float acc = 0.f;
            for (int i = 0; i < 2; ++i)
                for (int oy = 0; oy < 5; ++oy) {
                    int yy = iy2 + oy - 2; if (yy < 0 || yy >= 32) continue;
                    for (int ox = 0; ox < 5; ++ox) {
                        int xx = ix2 + ox - 2; if (xx < 0 || xx >= 32) continue;
                        acc += WeffI[i*25 + oy*5 + ox] * sX1[i][yy][xx];
                    }
                }
            if (iy2 == 0 || iy2 == 31 || ix2 == 0 || ix2 == 31) {
                float corr = 0.f;
                for (int by = 0; by < 3; ++by)
                    for (int bx = 0; bx < 3; ++bx) {
                        int qy = iy2 + by - 1, qx = ix2 + bx - 1;
                        if (qy >= 0 && qy < 32 && qx >= 0 && qx < 32) continue;
                        const float* Gb = GI + (by*3+bx)*18;
                        for (int i = 0; i < 2; ++i)
                            for (int ay = 0; ay < 3; ++ay) {
                                int yy2 = qy + ay - 1; if (yy2 < 0 || yy2 >= 32) continue;
                                for (int ax = 0; ax < 3; ++ax) {
                                    int xx2 = qx + ax - 1; if (xx2 < 0 || xx2 >= 32) continue;
                                    corr += Gb[i*9 + ay*3 + ax] * sX1[i][yy2][xx2];
                                }
                            }
                    }
                acc -= corr;
            }
            sr1[1+iy2][1+ix2] = acc;
        }
        // publish P2 (value 1); wait for neighbors' P2 before reading sr1
        REL_NB2(sMI, rpw, 1);
        SPIN_NB2(sMI, rpw, 1);

        // static B fragments for the 8 inner tiles (k0-8 = r)
        unsigned BsI0[8], BsI1[8], BsI2[8], BsI3[8];
        #pragma unroll
        for (int tt = 0; tt < 8; ++tt) {
            const int lr = 4*rpw + (tt >> 1);
            const int px = (tt & 1) * 16 + col;
            unsigned a0 = 0, a1 = 0, a2 = 0, a3 = 0;
            if (g == 0) {            // k0-7 = r taps 0-7
                a0 = pk(sr1[lr][px],     sr1[lr][px+1]);
                a1 = pk(sr1[lr][px+2],   sr1[lr+1][px]);
                a2 = pk(sr1[lr+1][px+1], sr1[lr+1][px+2]);
                a3 = pk(sr1[lr+2][px],   sr1[lr+2][px+1]);
            } else if (g == 1) {     // k8 = r tap 8 (low half of dword0)
                a0 = f2bf(sr1[lr+2][px+2]);
            }
            BsI0[tt] = a0; BsI1[tt] = a1; BsI2[tt] = a2; BsI3[tt] = a3;
            asm volatile("" : "+v"(BsI0[tt]), "+v"(BsI1[tt]),
                              "+v"(BsI2[tt]), "+v"(BsI3[tt]));
        }
        float vsumI[8] = {0.f, 0.f, 0.f, 0.f, 0.f, 0.f, 0.f, 0.f};
        for (int K = 0; K < 16; ++K) {
            const int cur = K & 1, nxt = cur ^ 1;
            union { u32x4 u; bf16x8 b; } av;
            av.u = *(const u32x4*)&sAI[K][lane][0];
            SPIN_NB2(sMI, rpw, K + 1);
            __builtin_amdgcn_s_setprio(1);
            ITILE(0); ITILE(1); ITILE(2); ITILE(3);
            ITILE(4); ITILE(5); ITILE(6); ITILE(7);
            __builtin_amdgcn_s_setprio(0);
            REL_NB2(sMI, rpw, K + 2);
        }
        // v1 = sum/4 -> sr1
        #pragma unroll
        for (int tt = 0; tt < 8; ++tt) {
            const int lr = 4*rpw + (tt >> 1);
            const int px = (tt & 1) * 16 + col;
            if (lane < 16) sr1[lr + 1][px + 1] = vsumI[tt] * 0.25f;
        }
    } else {
        // ---------------- waves 8-15: P5 (outer conv r -> sr) -------------
        const float* WeffO = ws;
        const float* GO    = ws + 64;
        int c = t & 63;
        for (int ar = (t >> 6) - 8; ar < 34; ar += 8) {
            int gg = gr0 + ar - 1;
            if ((unsigned)gg < 64u) {
                float acc = 0.f;
                for (int i = 0; i < 2; ++i)
                    for (int oy = 0; oy < 5; ++oy) {
                        int yy = gg + oy - 2; if (yy < 0 || yy >= 64) continue;
                        for (int ox = 0; ox < 5; ++ox) {
                            int xx = c + ox - 2; if (xx < 0 || xx >= 64) continue;
                            acc += WeffO[i*25 + oy*5 + ox] * sX[i][yy][xx];
                        }
                    }
                if (gg == 0 || gg == 63 || c == 0 || c == 63) {
                    float corr = 0.f;
                    for (int by = 0; by < 3; ++by)
                        for (int bx = 0; bx < 3; ++bx) {
                            int qy = gg + by - 1, qx = c + bx - 1;
                            if (qy >= 0 && qy < 64 && qx >= 0 && qx < 64) continue;
                            const float* Gb = GO + (by*3+bx)*18;
                            for (int i = 0; i < 2; ++i)
                                for (int ay = 0; ay < 3; ++ay) {
                                    int yy2 = qy + ay - 1; if (yy2 < 0 || yy2 >= 64) continue;
                                    for (int ax = 0; ax < 3; ++ax) {
                                        int xx2 = qx + ax - 1; if (xx2 < 0 || xx2 >= 64) continue;
                                        corr += Gb[i*9 + ay*3 + ax] * sX[i][yy2][xx2];
                                    }
                                }
                        }
                    acc -= corr;
                }
                sr[ar][1+c] = acc;
            }
        }
    }
    __syncthreads();   // join: v1 (sr1) and sr both complete

    // ---- P4: m = bilinear upsample(v1); rows gr0-1..gr0+32 (all waves) ----
    {
        int c = t & 63;
        for (int ar = t >> 6; ar < 34; ar += 16) {
            int gg = gr0 + ar - 1;
            if ((unsigned)gg < 64u) {
                int y0, y1; float wy0, wy1;
                if ((gg & 1) == 0) { y1 = gg >> 1; y0 = (y1 > 0) ? y1 - 1 : 0; wy1 = 0.75f; wy0 = 0.25f; }
                else               { y0 = gg >> 1; y1 = (y0 < 31) ? y0 + 1 : 31; wy0 = 0.75f; wy1 = 0.25f; }
                int xa, xb; float wx0, wx1;
                if ((c & 1) == 0) { xb = c >> 1; xa = (xb > 0) ? xb - 1 : 0; wx1 = 0.75f; wx0 = 0.25f; }
                else              { xa = c >> 1; xb = (xa < 31) ? xa + 1 : 31; wx0 = 0.75f; wx1 = 0.25f; }
                sm[ar][1+c] = wy0 * (wx0 * sr1[1+y0][1+xa] + wx1 * sr1[1+y0][1+xb])
                            + wy1 * (wx0 * sr1[1+y1][1+xa] + wx1 * sr1[1+y1][1+xb]);
            }
        }
    }
    __syncthreads();

    // ---- P6: outer VI via MFMA, boundary-first (compile-time order) ----
    const int rp   = rpw;                     // wave id
    const int pp   = half ? rp : (15 - rp);   // local row-pair index
    const int gRowV = half ? 0 : 33;          // bf16 ghost row

    // static B fragments (m,r slices), 4 regs x 8 tiles -- pinned
    unsigned Bs0[8], Bs1[8], Bs2[8], Bs3[8];
    #pragma unroll
    for (int tt = 0; tt < 8; ++tt) {
        const int lr = 2*pp + (tt >> 2);
        const int px = (tt & 3) * 16 + col;
        unsigned a0 = 0, a1 = 0, a2 = 0, a3 = 0;
        if (g == 0) {            // k0-7 = m taps 0-7
            a0 = pk(sm[lr][px],     sm[lr][px+1]);
            a1 = pk(sm[lr][px+2],   sm[lr+1][px]);
            a2 = pk(sm[lr+1][px+1], sm[lr+1][px+2]);
            a3 = pk(sm[lr+2][px],   sm[lr+2][px+1]);
        } else if (g == 1) {     // k8-15 = m tap 8, r taps 0-6
            a0 = pk(sm[lr+2][px+2], sr[lr][px]);
            a1 = pk(sr[lr][px+1],   sr[lr][px+2]);
            a2 = pk(sr[lr+1][px],   sr[lr+1][px+1]);
            a3 = pk(sr[lr+1][px+2], sr[lr+2][px]);
        } else if (g == 2) {     // k16-17 = r taps 7,8 (k18-23 = v, dynamic)
            a0 = pk(sr[lr+2][px+1], sr[lr+2][px+2]);
        }                        // g3: k24-26 = v (dynamic), k27-31 = 0
        Bs0[tt] = a0; Bs1[tt] = a1; Bs2[tt] = a2; Bs3[tt] = a3;
        asm volatile("" : "+v"(Bs0[tt]), "+v"(Bs1[tt]),
                          "+v"(Bs2[tt]), "+v"(Bs3[tt]));
    }

    float vsum[8];
    #pragma unroll
    for (int j = 0; j < 8; ++j) vsum[j] = 0.f;

    unsigned short*       ghU = (unsigned short*)ghMine;
    const unsigned short* gpU = (const unsigned short*)ghPart;

    for (int K = 0; K < 16; ++K) {
        const int cur = K & 1, nxt = cur ^ 1;
        union { u32x4 u; bf16x8 b; } av;
        av.u = *(const u32x4*)&sA[K][lane][0];   // static; overlaps spin
        SPIN_NB2(sMO, rp, K);                    // neighbors' v_K rows ready
        __builtin_amdgcn_s_setprio(1);
        // Boundary tiles first, literal tile indices; flag mid-step.
        if (!half) {   // boundary = tt 4-7 (local row 2pp+1)
            OTILE(4); OTILE(5); OTILE(6); OTILE(7);
            if (K < 15 && t == 0)
                __hip_atomic_store(flagMine, K + 1, __ATOMIC_RELEASE, SCOPE_AGENT);
            OTILE(0); OTILE(1); OTILE(2); OTILE(3);
        } else {       // boundary = tt 0-3 (local row 2pp)
            OTILE(0); OTILE(1); OTILE(2); OTILE(3);
            if (K < 15 && t == 0)
                __hip_atomic_store(flagMine, K + 1, __ATOMIC_RELEASE, SCOPE_AGENT);
            OTILE(4); OTILE(5); OTILE(6); OTILE(7);
        }
        __builtin_amdgcn_s_setprio(0);
        // early neighbor release (ghost row consumed only by wave 0 itself)
        REL_NB2(sMO, rp, K + 1);
        // deferred poll: partner posted its flag mid-step -> usually no wait
        if (K < 15 && rp == 0) {
            if (t == 0) {
                int spins = 0;
                while (__hip_atomic_load(flagPart, __ATOMIC_ACQUIRE, SCOPE_AGENT) < K + 1) {
                    __builtin_amdgcn_s_sleep(1);
                    if (++spins > (1 << 23)) break;   // safety valve
                }
            }
            vL[nxt][gRowV][lane + 1] = gpU[cur * 64 + lane];
        }
    }
    __syncthreads();

    // ---- v-sum -> sVb; exchange boundary sums (f32, flag 16) ----
    #pragma unroll
    for (int tt = 0; tt < 8; ++tt) {
        const int lr = 2*pp + (tt >> 2);
        const int px = (tt & 3) * 16 + col;
        if (lane < 16) sVb[lr + 1][px + 1] = vsum[tt];
    }
    if (rp == 0) {
        const int bAr = half ? 1 : 32;   // own boundary row (written above)
        const int gAr = half ? 0 : 33;   // ghost row
        float sv = sVb[bAr][1 + lane];
        __hip_atomic_store(ghMine + 128 + lane, sv, __ATOMIC_RELAXED, SCOPE_AGENT);
        if (t == 0) {
            __hip_atomic_store(flagMine, 16, __ATOMIC_RELEASE, SCOPE_AGENT);
            int spins = 0;
            while (__hip_atomic_load(flagPart, __ATOMIC_ACQUIRE, SCOPE_AGENT) < 16) {
                __builtin_amdgcn_s_sleep(1);
                if (++spins > (1 << 23)) break;
            }
        }
        sVb[gAr][1 + lane] =
            __hip_atomic_load(ghPart + 128 + lane, __ATOMIC_RELAXED, SCOPE_AGENT);
    }
    __syncthreads();

    // ---- P7: final conv (w15) on {m, r, vbar=sum/16} + BN + (S1,S2) pick ----
    {
        const float* wk = conv_q_ws + 15 * 270;
        const int oc = lane;
        float pm[4][3], pq[4][3], pv[4][3];
        #pragma unroll
        for (int dy = 0; dy < 4; ++dy)
            #pragma unroll
            for (int dx = 0; dx < 3; ++dx) {
                pm[dy][dx] = sm[2*pp+dy][oc+dx];
                pq[dy][dx] = sr[2*pp+dy][oc+dx];
                pv[dy][dx] = sVb[2*pp+dy][oc+dx] * 0.0625f;
            }
        int sy = S1[n], sx = S2[n];
        int ry0 = gr0 + 2*pp, ry1 = ry0 + 1;
        float* qpix = wsm + 544 + n * 10;
        #pragma unroll
        for (int ch = 0; ch < 10; ++ch) {
            const float* wc = wk + ch * 27;
            float q0 = 0.f, q1 = 0.f;
            #pragma unroll
            for (int ky = 0; ky < 3; ++ky)
                #pragma unroll
                for (int kx = 0; kx < 3; ++kx) {
                    float wm = wc[ky*3+kx];
                    float wr = wc[9  + ky*3+kx];
                    float wv = wc[18 + ky*3+kx];
                    q0 += wm * pm[ky][kx]   + wr * pq[ky][kx]   + wv * pv[ky][kx];
                    q1 += wm * pm[ky+1][kx] + wr * pq[ky+1][kx] + wv * pv[ky+1][kx];
                }
            if (oc == sx) {
                if (ry0 == sy) qpix[ch] = q0;
                if (ry1 == sy) qpix[ch] = q1;
            }
            float ls = q0 + q1, lq = q0*q0 + q1*q1;
            #pragma unroll
            for (int off = 32; off > 0; off >>= 1) {
                ls += __shfl_down(ls, off);
                lq += __shfl_down(lq, off);
            }
            if ((t & 63) == 0) {
                atomicAdd(&sRed[ch][0], ls);
                atomicAdd(&sRed[ch][1], lq);
            }
        }
        __syncthreads();
        if (t < 10) {
            atomicAdd(wsm + 512 + t, sRed[t][0]);
            atomicAdd(wsm + 528 + t, sRed[t][1]);
        }
    }
}

__global__ void k_final(const float* __restrict__ ws,
                        const float* __restrict__ gamma,
                        const float* __restrict__ beta,
                        const float* __restrict__ w1,
                        const float* __restrict__ w2,
                        float* __restrict__ out) {
    int n = threadIdx.x;
    if (n >= 128) return;
    const float inv = 1.f / 524288.f;
    float qn[10];
    for (int c = 0; c < 10; ++c) {
        float mean = ws[512 + c] * inv;
        float var  = ws[528 + c] * inv - mean * mean;
        float q    = ws[544 + n * 10 + c];
        qn[c] = (q - mean) * rsqrtf(var + 1e-5f) * gamma[c] + beta[c];
    }
    float a = 0.f;
    for (int c = 0; c < 10; ++c) a += qn[c] * w1[c];
    a = fmaxf(a, 0.f);
    float b[8], mb = 0.f;
    for (int j = 0; j < 8; ++j) {
        float bj = 0.f;
        for (int c = 0; c < 10; ++c) bj += qn[c] * w2[j * 10 + c];
        bj = fmaxf(bj, 0.f);
        b[j] = bj;
        mb += bj;
    }
    mb *= 0.125f;
    for (int j = 0; j < 8; ++j) out[n * 8 + j] = a + b[j] - mb;
}

extern "C" void kernel_launch(void* const* d_in, const int* in_sizes, int n_in,
                              void* d_out, int out_size, void* d_ws, size_t ws_size,
                              hipStream_t stream) {
    const float* X         = (const float*)d_in[0];
    const int*   S1        = (const int*)  d_in[1];
    const int*   S2        = (const int*)  d_in[2];
    const float* conv_h_w  = (const float*)d_in[3];
    const float* conv_r_w  = (const float*)d_in[4];
    const float* conv_q_ws = (const float*)d_in[5];
    const float* bn_gamma  = (const float*)d_in[6];
    const float* bn_beta   = (const float*)d_in[7];
    const float* duel_w1   = (const float*)d_in[8];
    const float* duel_w2   = (const float*)d_in[9];
    const float* vi_h_w    = (const float*)d_in[10];
    const float* vi_r_w    = (const float*)d_in[11];
    const float* vi_q_ws   = (const float*)d_in[12];
    float* ws = (float*)d_ws;

    k_precomp<<<1, 1024, 0, stream>>>(conv_h_w, conv_r_w, vi_h_w, vi_r_w,
                                      conv_q_ws, vi_q_ws, ws);
    k_main<<<256, 1024, 0, stream>>>(X, S1, S2, conv_q_ws, vi_q_ws, ws, ws);
    k_final<<<1, 128, 0, stream>>>(ws, bn_gamma, bn_beta, duel_w1, duel_w2,
                                   (float*)d_out);
}